// Round 14
// baseline (15587.256 us; speedup 1.0000x reference)
//
#include <hip/hip_runtime.h>

typedef float f32x4 __attribute__((ext_vector_type(4)));
typedef short s16x8 __attribute__((ext_vector_type(8)));
typedef short s16x4 __attribute__((ext_vector_type(4)));

namespace kf {
constexpr int TN = 1024, NS = 64, NO = 32, NI = 16;
constexpr int PP = 72;   // u16 pitch, 64-col bf16 arrays
constexpr int PK = 40;   // u16 pitch, 32-col bf16 arrays

constexpr float ATAB[6][5] = {
  {0.f,0.f,0.f,0.f,0.f},
  {(float)(1.0/5.0),0.f,0.f,0.f,0.f},
  {(float)(3.0/40.0),(float)(9.0/40.0),0.f,0.f,0.f},
  {(float)(44.0/45.0),(float)(-56.0/15.0),(float)(32.0/9.0),0.f,0.f},
  {(float)(19372.0/6561.0),(float)(-25360.0/2187.0),(float)(64448.0/6561.0),(float)(-212.0/729.0),0.f},
  {(float)(9017.0/3168.0),(float)(-355.0/33.0),(float)(46732.0/5247.0),(float)(49.0/176.0),(float)(-5103.0/18656.0)},
};
constexpr float CTAB[6] = {0.f,(float)(1.0/5.0),(float)(3.0/10.0),(float)(4.0/5.0),(float)(8.0/9.0),1.f};
constexpr float BW0=(float)(35.0/384.0), BW2=(float)(500.0/1113.0), BW3=(float)(125.0/192.0),
                BW4=(float)(-2187.0/6784.0), BW5=(float)(11.0/84.0);

struct ShB {
  unsigned short Pib[80*PP];   // Pi augmented: row 64 = xi, rows 65-79 = 0
  unsigned short Ab [64*PP];
  unsigned short Cb [32*PP];
  unsigned short RCb[32*PP];   // -(Rinv C) -> KKb stores -K
  unsigned short KKb[64*PK];   // -K   (init: GJ scratch overlays KKb+GTb)
  unsigned short GTb[80*PK];   // GT; row 64 = (C@xi - y_c), rows 65-79 = 0
  float Bf[64*16];
  float BUB[2][64];
  float FAC[32];
  int HYP;
};
} // namespace kf
using namespace kf;

__device__ inline float bf2f(unsigned short u){
  unsigned int x = ((unsigned int)u) << 16; return __builtin_bit_cast(float, x);
}
__device__ inline unsigned short f2bf(float f){
  unsigned int x = __builtin_bit_cast(unsigned int, f);
  return (unsigned short)((x + 0x7fffu + ((x >> 16) & 1u)) >> 16);
}
__device__ __forceinline__ unsigned int pack2bf(float a, float b){
  return (unsigned int)f2bf(a) | ((unsigned int)f2bf(b) << 16);
}
__device__ inline s16x8 load_frag(const unsigned short* arr, int pitch, int row0, int k0, int hyp){
  const int l = (int)(threadIdx.x & 63), lc = l & 15, lg = l >> 4;
  const unsigned short* p = arr + (row0 + lc) * pitch + k0;
  if ((hyp & 1) == 0) {
    return *(const s16x8*)(p + lg * 8);
  } else {
    s16x4 a = *(const s16x4*)(p + lg * 4);
    s16x4 b = *(const s16x4*)(p + 16 + lg * 4);
    s16x8 r; r[0]=a[0]; r[1]=a[1]; r[2]=a[2]; r[3]=a[3]; r[4]=b[0]; r[5]=b[1]; r[6]=b[2]; r[7]=b[3];
    return r;
  }
}
__device__ inline f32x4 MF(s16x8 a, s16x8 b, f32x4 c, int hyp){
  if (hyp & 2) return __builtin_amdgcn_mfma_f32_16x16x32_bf16(b, a, c, 0, 0, 0);
  return __builtin_amdgcn_mfma_f32_16x16x32_bf16(a, b, c, 0, 0, 0);
}
template<int HYP>
__device__ __forceinline__ s16x8 load_fragT(const unsigned short* arr, int pitch, int row0, int k0){
  const int l = (int)(threadIdx.x & 63), lc = l & 15, lg = l >> 4;
  const unsigned short* p = arr + (row0 + lc) * pitch + k0;
  if constexpr ((HYP & 1) == 0) {
    return *(const s16x8*)(p + lg * 8);
  } else {
    s16x4 a = *(const s16x4*)(p + lg * 4);
    s16x4 b = *(const s16x4*)(p + 16 + lg * 4);
    s16x8 r; r[0]=a[0]; r[1]=a[1]; r[2]=a[2]; r[3]=a[3]; r[4]=b[0]; r[5]=b[1]; r[6]=b[2]; r[7]=b[3];
    return r;
  }
}
template<int HYP>
__device__ __forceinline__ f32x4 MFT(s16x8 a, s16x8 b, f32x4 c){
  if constexpr ((HYP & 2) != 0) return __builtin_amdgcn_mfma_f32_16x16x32_bf16(b, a, c, 0, 0, 0);
  else                          return __builtin_amdgcn_mfma_f32_16x16x32_bf16(a, b, c, 0, 0, 0);
}

// 16-wave layout (1024 threads, 4 waves/SIMD -> 128-VGPR cap per wave, kP in
// REGISTERS, no KPL LDS array): wave (sr = wid>>2, cq = wid&3) owns P tile
// (rows 16sr, cols 16cq). cq<2: also KK strip (ch=cq). cq>=2: GT strip
// (ch=cq-2). cq==0: x-side (APdX + kx slopes in regs). (sr==3,cq>=2): GTX row.
// Algebra identical to R12 (KKb = -K, GTX = Cx - y, folds via MFMA C-operand).
template<int HYP>
__device__ __forceinline__ void scan_body(ShB& sh,
    const float* __restrict__ ts, const float* __restrict__ ys, const float* __restrict__ us,
    const float* __restrict__ x0g, const float* __restrict__ P0g, const float* __restrict__ Qg,
    float* __restrict__ out)
{
  const int tid = (int)threadIdx.x;
  const int wid = tid >> 6, l = tid & 63;
  const int lc = l & 15, lg = l >> 4;
  const int sr = wid >> 2, cq = wid & 3;
  const int ch = (cq < 2) ? cq : (cq - 2);
  const int rowbase = 16*sr + 4*lg;
  const bool isx = (cq == 0);
  const bool isg = (sr == 3) && (cq >= 2);

  const float h = ts[1] - ts[0];
  f32x4 z4 = {0.f,0.f,0.f,0.f};
  f32x4 Pfr, Qfr, AP = z4, APdX = z4, XRv;
  f32x4 kP0=z4,kP1=z4,kP2=z4,kP3=z4,kP4=z4;
  f32x4 kx0=z4,kx1=z4,kx2=z4,kx3=z4,kx4=z4;
  s16x8 aA[2], bA[2], aW[2];
  f32x4 y1v = z4, y2v = z4;

  #pragma unroll
  for (int r = 0; r < 4; ++r) {
    int row = rowbase + r, col = 16*cq + lc;
    Pfr[r] = P0g[row*64 + col];
    Qfr[r] = Qg [row*64 + col];
  }
  #pragma unroll
  for (int kb = 0; kb < 2; ++kb) {
    aA[kb] = load_fragT<HYP>(sh.Ab, PP, 16*sr, 32*kb);
    bA[kb] = load_fragT<HYP>(sh.Ab, PP, 16*cq, 32*kb);
    if (cq < 2) aW[kb] = load_fragT<HYP>(sh.RCb, PP, 16*ch, 32*kb);
    else        aW[kb] = load_fragT<HYP>(sh.Cb,  PP, 16*ch, 32*kb);
  }
  XRv = *(const f32x4*)&x0g[rowbase];
  if (isg) {
    y1v = *(const f32x4*)&ys[16*ch + 4*lg];
    y2v = *(const f32x4*)&ys[NO + 16*ch + 4*lg];
  }
  if (tid < 64) {
    out[tid] = x0g[tid];
    sh.Pib[64*PP + tid] = f2bf(x0g[tid]);
    const f32x4* bf4 = (const f32x4*)&sh.Bf[tid*16];
    const f32x4* up4 = (const f32x4*)us;
    float bu = 0.f;
    #pragma unroll
    for (int m4 = 0; m4 < 4; ++m4) {
      f32x4 b = bf4[m4], u = up4[m4];
      bu += b.x*u.x + b.y*u.y + b.z*u.z + b.w*u.w;
    }
    sh.BUB[0][tid] = bu;
  }
  for (int idx = tid; idx < 15*PP; idx += 1024) sh.Pib[65*PP + idx] = 0;
  if (tid < PP - 64) sh.Pib[64*PP + 64 + tid] = 0;
  for (int idx = tid; idx < 16*PK; idx += 1024) sh.GTb[64*PK + idx] = 0;
  __syncthreads();

  for (int t = 0; t < TN - 1; ++t) {
    #pragma unroll
    for (int st = 0; st < 6; ++st) {
      // ================= PHASE A =================
      if (t > 0 || st > 0) {
        s16x8 am = load_fragT<HYP>(sh.KKb, PK, 16*sr, 0);   // -K rows 16sr
        s16x8 bg = load_fragT<HYP>(sh.GTb, PK, 16*cq, 0);
        f32x4 kPv = MFT<HYP>(am, bg, AP);                   // AP - K@G
        f32x4 x;
        if (st == 0) {
          Pfr += h * (BW0*kP0 + BW2*kP2 + BW3*kP3 + BW4*kP4 + BW5*kPv + Qfr);
          x = Pfr;
        } else {
          x = Pfr + (h * CTAB[st]) * Qfr + (h * ATAB[st][st-1]) * kPv;
          if (st >= 2) x += (h * ATAB[st][0]) * kP0;
          if (st >= 3) x += (h * ATAB[st][1]) * kP1;
          if (st >= 4) x += (h * ATAB[st][2]) * kP2;
          if (st >= 5) x += (h * ATAB[st][3]) * kP3;
          if (st == 1) kP0 = kPv; else if (st == 2) kP1 = kPv;
          else if (st == 3) kP2 = kPv; else if (st == 4) kP3 = kPv; else kP4 = kPv;
        }
        uint2 pk; pk.x = pack2bf(x[0], x[1]); pk.y = pack2bf(x[2], x[3]);
        *(uint2*)&sh.Pib[(16*cq + lc)*PP + rowbase] = pk;   // transpose-pack
        // ---- x-side (cq==0 waves): kx = A@xi + K(y-Cx) + Bu, all-reg slopes ----
        if (isx) {
          s16x8 bgX = load_fragT<HYP>(sh.GTb, PK, 64, 0);
          f32x4 kx = MFT<HYP>(am, bgX, APdX);
          {
            f32x4 bu1 = *(const f32x4*)&sh.BUB[t & 1][rowbase];
            if (st == 0) {
              kx += bu1;
            } else {
              const float cp = CTAB[st-1];
              if (cp != 0.f) {
                f32x4 bu2 = *(const f32x4*)&sh.BUB[(t + 1) & 1][rowbase];
                kx += (1.f - cp) * bu1 + cp * bu2;
              } else {
                kx += bu1;
              }
            }
          }
          f32x4 xiv;
          if (st == 0) {
            XRv += h * (BW0*kx0 + BW2*kx2 + BW3*kx3 + BW4*kx4 + BW5*kx);
            if (lc == 0) *(f32x4*)&out[(size_t)t*64 + rowbase] = XRv;
            xiv = XRv;
          } else {
            xiv = XRv + (h * ATAB[st][st-1]) * kx;
            if (st >= 2 && ATAB[st][0] != 0.f) xiv += (h * ATAB[st][0]) * kx0;
            if (st >= 3 && ATAB[st][1] != 0.f) xiv += (h * ATAB[st][1]) * kx1;
            if (st >= 4 && ATAB[st][2] != 0.f) xiv += (h * ATAB[st][2]) * kx2;
            if (st >= 5 && ATAB[st][3] != 0.f) xiv += (h * ATAB[st][3]) * kx3;
            if (st == 1) kx0 = kx; else if (st == 2) kx1 = kx;
            else if (st == 3) kx2 = kx; else if (st == 4) kx3 = kx; else kx4 = kx;
          }
          if (lc == 0) {
            uint2 pk2; pk2.x = pack2bf(xiv[0], xiv[1]); pk2.y = pack2bf(xiv[2], xiv[3]);
            *(uint2*)&sh.Pib[64*PP + rowbase] = pk2;
          }
        }
      } else {
        // t==0, st==0: initial pack; xi row already = x0
        uint2 pk; pk.x = pack2bf(Pfr[0], Pfr[1]); pk.y = pack2bf(Pfr[2], Pfr[3]);
        *(uint2*)&sh.Pib[(16*cq + lc)*PP + rowbase] = pk;
      }
      __syncthreads();
      // ================= PHASE B =================
      {
        s16x8 aPi0 = load_fragT<HYP>(sh.Pib, PP, 16*sr, 0);
        s16x8 aPi1 = load_fragT<HYP>(sh.Pib, PP, 16*sr, 32);
        s16x8 bP0  = load_fragT<HYP>(sh.Pib, PP, 16*cq, 0);
        s16x8 bP1  = load_fragT<HYP>(sh.Pib, PP, 16*cq, 32);
        f32x4 acc = MFT<HYP>(aA[0], bP0, z4);
        acc = MFT<HYP>(aA[1], bP1, acc);
        acc = MFT<HYP>(aPi0, bA[0], acc);
        AP  = MFT<HYP>(aPi1, bA[1], acc);
        f32x4 aKG = MFT<HYP>(aW[1], aPi1, MFT<HYP>(aW[0], aPi0, z4));
        uint2 pkk; pkk.x = pack2bf(aKG[0], aKG[1]); pkk.y = pack2bf(aKG[2], aKG[3]);
        if (cq < 2) *(uint2*)&sh.KKb[(16*sr + lc)*PK + 16*ch + 4*lg] = pkk;
        else        *(uint2*)&sh.GTb[(16*sr + lc)*PK + 16*ch + 4*lg] = pkk;
      }
      if (isx || isg) {
        s16x8 px0 = load_fragT<HYP>(sh.Pib, PP, 64, 0);
        s16x8 px1 = load_fragT<HYP>(sh.Pib, PP, 64, 32);
        if (isx) {
          APdX = MFT<HYP>(aA[1], px1, MFT<HYP>(aA[0], px0, z4));
        } else {
          f32x4 gx = MFT<HYP>(aW[1], px1, MFT<HYP>(aW[0], px0, z4));
          const float c = CTAB[st];
          f32x4 v;
          #pragma unroll
          for (int r = 0; r < 4; ++r) {
            float yc = (1.f - c) * y1v[r] + c * y2v[r];
            v[r] = gx[r] - yc;            // (Cx - y): sign pairs with -K
          }
          uint2 pk;
          if (lc == 0) { pk.x = pack2bf(v[0], v[1]); pk.y = pack2bf(v[2], v[3]); }
          else         { pk.x = 0u; pk.y = 0u; }
          *(uint2*)&sh.GTb[(64 + lc)*PK + 16*ch + 4*lg] = pk;
        }
      }
      if (st == 0 && wid == 1) {   // BUB for u[t+1] on wave 1 (no x-side load)
        const f32x4* bf4 = (const f32x4*)&sh.Bf[l*16];
        const f32x4* up4 = (const f32x4*)(us + (size_t)(t + 1)*NI);
        float bu = 0.f;
        #pragma unroll
        for (int m4 = 0; m4 < 4; ++m4) {
          f32x4 b = bf4[m4], u = up4[m4];
          bu += b.x*u.x + b.y*u.y + b.z*u.z + b.w*u.w;
        }
        sh.BUB[(t + 1) & 1][l] = bu;
      }
      __syncthreads();
    } // stages
    if (isg) {
      y1v = y2v;
      if (t + 2 < TN) y2v = *(const f32x4*)&ys[(size_t)(t + 2)*NO + 16*ch + 4*lg];
    }
  } // t

  // tail: slope k5 of last step + final x combine
  if (isx) {
    s16x8 am  = load_fragT<HYP>(sh.KKb, PK, 16*sr, 0);
    s16x8 bgX = load_fragT<HYP>(sh.GTb, PK, 64, 0);
    f32x4 kx = MFT<HYP>(am, bgX, APdX);
    kx += *(const f32x4*)&sh.BUB[(TN - 1) & 1][rowbase];
    XRv += h * (BW0*kx0 + BW2*kx2 + BW3*kx3 + BW4*kx4 + BW5*kx);
    if (lc == 0) *(f32x4*)&out[(size_t)(TN - 1)*64 + rowbase] = XRv;
  }
}

__global__ __launch_bounds__(1024, 1)
void kf_mfma13(const float* __restrict__ ts, const float* __restrict__ ys,
               const float* __restrict__ us, const float* __restrict__ Ag,
               const float* __restrict__ Bg, const float* __restrict__ Cg,
               const float* __restrict__ x0g, const float* __restrict__ P0g,
               const float* __restrict__ Qg, const float* __restrict__ Rg,
               float* __restrict__ out)
{
  __shared__ ShB sh;
  __shared__ float Xref[256];
  float* GJ = (float*)sh.KKb;   // init-only overlay (KKb+GTb = 11.5KB >= 8KB)
  const int tid = (int)threadIdx.x;
  const int wv = tid >> 6;
  const int lc = tid & 15, lg = (tid & 63) >> 4;

  for (int idx = tid; idx < 64*64; idx += 1024) sh.Ab[(idx>>6)*PP + (idx&63)] = f2bf(Ag[idx]);
  for (int idx = tid; idx < 32*64; idx += 1024) sh.Cb[(idx>>6)*PP + (idx&63)] = f2bf(Cg[idx]);
  for (int idx = tid; idx < 64*16; idx += 1024) sh.Bf[idx] = Bg[idx];
  for (int idx = tid; idx < 32*64; idx += 1024) {
    int r = idx >> 6, c = idx & 63;
    GJ[idx] = (c < 32) ? Rg[r*32 + c] : ((c - 32) == r ? 1.f : 0.f);
  }
  __syncthreads();
  for (int k2 = 0; k2 < 32; ++k2) {
    if (tid < 32) sh.FAC[tid] = GJ[tid*64 + k2];
    __syncthreads();
    const float pinv = 1.f / sh.FAC[k2];
    float oldv[2], vk[2];
    #pragma unroll
    for (int s = 0; s < 2; ++s) {
      int idx = tid + s*1024;
      oldv[s] = GJ[idx];
      vk[s]   = GJ[k2*64 + (idx & 63)];
    }
    __syncthreads();
    #pragma unroll
    for (int s = 0; s < 2; ++s) {
      int idx = tid + s*1024, i = idx >> 6;
      GJ[idx] = (i == k2) ? (oldv[s] * pinv) : (oldv[s] - sh.FAC[i] * (vk[s] * pinv));
    }
    __syncthreads();
  }
  for (int idx = tid; idx < 32*64; idx += 1024) {   // RCb = -(Rinv @ C)
    int q = idx >> 6, k = idx & 63;
    float a = 0.f;
    for (int p = 0; p < 32; ++p) a += GJ[q*64 + 32 + p] * Cg[p*64 + k];
    sh.RCb[q*PP + k] = f2bf(-a);
  }
  __syncthreads();
  if (tid < 256) {
    int r = tid >> 4, c = tid & 15;
    float a = 0.f;
    for (int k = 0; k < 32; ++k) a += bf2f(sh.Ab[r*PP + k]) * bf2f(sh.Ab[(16 + c)*PP + k]);
    Xref[tid] = a;
  }
  if (tid == 0) sh.HYP = -1;
  __syncthreads();
  for (int hh = 0; hh < 4; ++hh) {
    if (wv == 0) {
      s16x8 af = load_frag(sh.Ab, PP, 0, 0, hh);
      s16x8 bf = load_frag(sh.Ab, PP, 16, 0, hh);
      f32x4 z = {0.f,0.f,0.f,0.f};
      f32x4 d = MF(af, bf, z, hh);
      int ok = 1;
      #pragma unroll
      for (int r = 0; r < 4; ++r) {
        float rf = Xref[(lg*4 + r)*16 + lc];
        ok &= (fabsf(d[r] - rf) <= 1e-3f + 1e-2f * fabsf(rf)) ? 1 : 0;
      }
      if (__all(ok) && tid == 0) { if (sh.HYP < 0) sh.HYP = hh; }
    }
    __syncthreads();
  }
  const int sHyp = (sh.HYP < 0) ? 0 : sh.HYP;

  switch (sHyp) {
    case 0: scan_body<0>(sh, ts, ys, us, x0g, P0g, Qg, out); break;
    case 1: scan_body<1>(sh, ts, ys, us, x0g, P0g, Qg, out); break;
    case 2: scan_body<2>(sh, ts, ys, us, x0g, P0g, Qg, out); break;
    default: scan_body<3>(sh, ts, ys, us, x0g, P0g, Qg, out); break;
  }
}

extern "C" void kernel_launch(void* const* d_in, const int* in_sizes, int n_in,
                              void* d_out, int out_size, void* d_ws, size_t ws_size,
                              hipStream_t stream) {
  (void)in_sizes; (void)n_in; (void)out_size; (void)d_ws; (void)ws_size;
  const float* ts  = (const float*)d_in[0];
  const float* ys  = (const float*)d_in[1];
  const float* us  = (const float*)d_in[2];
  const float* A   = (const float*)d_in[3];
  const float* B   = (const float*)d_in[4];
  const float* C   = (const float*)d_in[5];
  const float* x0  = (const float*)d_in[6];
  const float* P0  = (const float*)d_in[7];
  const float* Q   = (const float*)d_in[8];
  const float* R   = (const float*)d_in[9];
  hipLaunchKernelGGL(kf_mfma13, dim3(1), dim3(1024), 0, stream,
                     ts, ys, us, A, B, C, x0, P0, Q, R, (float*)d_out);
}

// Round 15
// 7159.431 us; speedup vs baseline: 2.1772x; 2.1772x over previous
//
#include <hip/hip_runtime.h>

typedef float f32x4 __attribute__((ext_vector_type(4)));
typedef short s16x8 __attribute__((ext_vector_type(8)));
typedef short s16x4 __attribute__((ext_vector_type(4)));

namespace kf {
constexpr int TN = 1024, NS = 64, NO = 32, NI = 16;
constexpr int PP = 72;   // u16 pitch, 64-col bf16 arrays
constexpr int PK = 40;   // u16 pitch, 32-col bf16 arrays
constexpr int PKP = 68;  // f32 pitch for kP store

constexpr float ATAB[6][5] = {
  {0.f,0.f,0.f,0.f,0.f},
  {(float)(1.0/5.0),0.f,0.f,0.f,0.f},
  {(float)(3.0/40.0),(float)(9.0/40.0),0.f,0.f,0.f},
  {(float)(44.0/45.0),(float)(-56.0/15.0),(float)(32.0/9.0),0.f,0.f},
  {(float)(19372.0/6561.0),(float)(-25360.0/2187.0),(float)(64448.0/6561.0),(float)(-212.0/729.0),0.f},
  {(float)(9017.0/3168.0),(float)(-355.0/33.0),(float)(46732.0/5247.0),(float)(49.0/176.0),(float)(-5103.0/18656.0)},
};
constexpr float CTAB[6] = {0.f,(float)(1.0/5.0),(float)(3.0/10.0),(float)(4.0/5.0),(float)(8.0/9.0),1.f};
constexpr float BW0=(float)(35.0/384.0), BW2=(float)(500.0/1113.0), BW3=(float)(125.0/192.0),
                BW4=(float)(-2187.0/6784.0), BW5=(float)(11.0/84.0);

struct ShB {
  unsigned short Pib[80*PP];   // Pi augmented: row 64 = xi, rows 65-79 = 0
  unsigned short Ab [64*PP];
  unsigned short Cb [32*PP];
  unsigned short RCb[32*PP];   // holds -(Rinv C): KKb then stores -K (M/kx folds)
  unsigned short KKb[64*PK];   // -K
  unsigned short GTb[80*PK];   // GT; row 64 = (C@xi - y_c), rows 65-79 = 0
  float Bf[64*16];
  float BUB[2][64];
  float KXL[5][64];
  float FAC[32];
  int HYP;
};
constexpr size_t SH_BASE  = (sizeof(ShB) + 255) & ~size_t(255);
constexpr size_t SH_TOTAL = SH_BASE + size_t(5*64*PKP)*4;
} // namespace kf
using namespace kf;

__device__ inline float bf2f(unsigned short u){
  unsigned int x = ((unsigned int)u) << 16; return __builtin_bit_cast(float, x);
}
__device__ inline unsigned short f2bf(float f){
  unsigned int x = __builtin_bit_cast(unsigned int, f);
  return (unsigned short)((x + 0x7fffu + ((x >> 16) & 1u)) >> 16);
}
__device__ __forceinline__ unsigned int pack2bf(float a, float b){
  return (unsigned int)f2bf(a) | ((unsigned int)f2bf(b) << 16);
}
__device__ inline s16x8 load_frag(const unsigned short* arr, int pitch, int row0, int k0, int hyp){
  const int l = (int)(threadIdx.x & 63), lc = l & 15, lg = l >> 4;
  const unsigned short* p = arr + (row0 + lc) * pitch + k0;
  if ((hyp & 1) == 0) {
    return *(const s16x8*)(p + lg * 8);
  } else {
    s16x4 a = *(const s16x4*)(p + lg * 4);
    s16x4 b = *(const s16x4*)(p + 16 + lg * 4);
    s16x8 r; r[0]=a[0]; r[1]=a[1]; r[2]=a[2]; r[3]=a[3]; r[4]=b[0]; r[5]=b[1]; r[6]=b[2]; r[7]=b[3];
    return r;
  }
}
__device__ inline f32x4 MF(s16x8 a, s16x8 b, f32x4 c, int hyp){
  if (hyp & 2) return __builtin_amdgcn_mfma_f32_16x16x32_bf16(b, a, c, 0, 0, 0);
  return __builtin_amdgcn_mfma_f32_16x16x32_bf16(a, b, c, 0, 0, 0);
}
template<int HYP>
__device__ __forceinline__ s16x8 load_fragT(const unsigned short* arr, int pitch, int row0, int k0){
  const int l = (int)(threadIdx.x & 63), lc = l & 15, lg = l >> 4;
  const unsigned short* p = arr + (row0 + lc) * pitch + k0;
  if constexpr ((HYP & 1) == 0) {
    return *(const s16x8*)(p + lg * 8);
  } else {
    s16x4 a = *(const s16x4*)(p + lg * 4);
    s16x4 b = *(const s16x4*)(p + 16 + lg * 4);
    s16x8 r; r[0]=a[0]; r[1]=a[1]; r[2]=a[2]; r[3]=a[3]; r[4]=b[0]; r[5]=b[1]; r[6]=b[2]; r[7]=b[3];
    return r;
  }
}
template<int HYP>
__device__ __forceinline__ f32x4 MFT(s16x8 a, s16x8 b, f32x4 c){
  if constexpr ((HYP & 2) != 0) return __builtin_amdgcn_mfma_f32_16x16x32_bf16(b, a, c, 0, 0, 0);
  else                          return __builtin_amdgcn_mfma_f32_16x16x32_bf16(a, b, c, 0, 0, 0);
}

// Best-known configuration (R12, 7169 us): 512 threads / 8 waves (2 waves/SIMD
// TLP at the empirical 128-VGPR cap), kP slopes in LDS (KPL), augmented-state
// x-dynamics folded into the P-side MFMAs, KKb = -K / GTX = (Cx - y) sign
// convention so kP and kx fold into MFMA C-operands.
template<int HYP>
__device__ __forceinline__ void scan_body(ShB& sh, float* __restrict__ KPL,
    const float* __restrict__ ts, const float* __restrict__ ys, const float* __restrict__ us,
    const float* __restrict__ x0g, const float* __restrict__ P0g, const float* __restrict__ Qg,
    float* __restrict__ out)
{
  const int tid = (int)threadIdx.x;
  const int w = tid >> 6, l = tid & 63;
  const int lc = l & 15, lg = l >> 4;
  const int sr = w & 3, ch = w >> 2;
  const int rowbase = 16*sr + 4*lg;
  const bool isx = (ch == 0);
  const bool isg = (sr == 3);

  const float h = ts[1] - ts[0];
  f32x4 z4 = {0.f,0.f,0.f,0.f};
  f32x4 Pfr[2], Qfr[2], AP[2], APdX, XRv;
  s16x8 aA[2], aRC[2], aC[2], bA[2][2];
  f32x4 y1v = z4, y2v = z4;
  #pragma unroll
  for (int c2 = 0; c2 < 2; ++c2) { Pfr[c2]=z4; Qfr[c2]=z4; AP[c2]=z4; }
  APdX = z4;

  #pragma unroll
  for (int c2 = 0; c2 < 2; ++c2)
    #pragma unroll
    for (int r = 0; r < 4; ++r) {
      int row = 16*sr + 4*lg + r, col = 16*(2*ch + c2) + lc;
      Pfr[c2][r] = P0g[row*64 + col];
      Qfr[c2][r] = Qg [row*64 + col];
    }
  #pragma unroll
  for (int kb = 0; kb < 2; ++kb) {
    aA [kb] = load_fragT<HYP>(sh.Ab,  PP, 16*sr, 32*kb);
    aRC[kb] = load_fragT<HYP>(sh.RCb, PP, 16*ch, 32*kb);
    aC [kb] = load_fragT<HYP>(sh.Cb,  PP, 16*ch, 32*kb);
    #pragma unroll
    for (int c2 = 0; c2 < 2; ++c2)
      bA[c2][kb] = load_fragT<HYP>(sh.Ab, PP, 16*(2*ch + c2), 32*kb);
  }
  XRv = *(const f32x4*)&x0g[rowbase];
  if (isg) {
    y1v = *(const f32x4*)&ys[16*ch + 4*lg];
    y2v = *(const f32x4*)&ys[NO + 16*ch + 4*lg];
  }
  if (tid < 64) {
    out[tid] = x0g[tid];
    sh.Pib[64*PP + tid] = f2bf(x0g[tid]);
    const f32x4* bf4 = (const f32x4*)&sh.Bf[tid*16];
    const f32x4* up4 = (const f32x4*)us;
    float bu = 0.f;
    #pragma unroll
    for (int m4 = 0; m4 < 4; ++m4) {
      f32x4 b = bf4[m4], u = up4[m4];
      bu += b.x*u.x + b.y*u.y + b.z*u.z + b.w*u.w;
    }
    sh.BUB[0][tid] = bu;
  }
  for (int idx = tid; idx < 15*PP; idx += 512) sh.Pib[65*PP + idx] = 0;
  if (tid < PP - 64) sh.Pib[64*PP + 64 + tid] = 0;
  for (int idx = tid; idx < 16*PK; idx += 512) sh.GTb[64*PK + idx] = 0;
  __syncthreads();

  for (int t = 0; t < TN - 1; ++t) {
    #pragma unroll
    for (int st = 0; st < 6; ++st) {
      // ================= PHASE A =================
      if (t > 0 || st > 0) {
        s16x8 am = load_fragT<HYP>(sh.KKb, PK, 16*sr, 0);   // -K rows
        #pragma unroll
        for (int c2 = 0; c2 < 2; ++c2) {
          const int ct = 2*ch + c2;
          s16x8 bg = load_fragT<HYP>(sh.GTb, PK, 16*ct, 0);
          f32x4 kPv = MFT<HYP>(am, bg, AP[c2]);             // AP + (-K)@G
          float* kbase = &KPL[(size_t)(16*ct + lc) * PKP + 16*sr + 4*lg];
          f32x4 x;
          if (st == 0) {
            f32x4 k0v = *(const f32x4*)(kbase + 0*64*PKP);
            f32x4 k2v = *(const f32x4*)(kbase + 2*64*PKP);
            f32x4 k3v = *(const f32x4*)(kbase + 3*64*PKP);
            f32x4 k4v = *(const f32x4*)(kbase + 4*64*PKP);
            #pragma unroll
            for (int r = 0; r < 4; ++r)
              Pfr[c2][r] += h * (BW0*k0v[r] + BW2*k2v[r] + BW3*k3v[r]
                               + BW4*k4v[r] + BW5*kPv[r] + Qfr[c2][r]);
            x = Pfr[c2];
          } else {
            *(f32x4*)(kbase + (size_t)(st-1)*64*PKP) = kPv;
            #pragma unroll
            for (int r = 0; r < 4; ++r)
              x[r] = Pfr[c2][r] + (h * CTAB[st]) * Qfr[c2][r] + (h * ATAB[st][st-1]) * kPv[r];
            if (st >= 2) { f32x4 kv = *(const f32x4*)(kbase + 0*64*PKP);
              #pragma unroll
              for (int r = 0; r < 4; ++r) x[r] += (h * ATAB[st][0]) * kv[r]; }
            if (st >= 3) { f32x4 kv = *(const f32x4*)(kbase + 1*64*PKP);
              #pragma unroll
              for (int r = 0; r < 4; ++r) x[r] += (h * ATAB[st][1]) * kv[r]; }
            if (st >= 4) { f32x4 kv = *(const f32x4*)(kbase + 2*64*PKP);
              #pragma unroll
              for (int r = 0; r < 4; ++r) x[r] += (h * ATAB[st][2]) * kv[r]; }
            if (st >= 5) { f32x4 kv = *(const f32x4*)(kbase + 3*64*PKP);
              #pragma unroll
              for (int r = 0; r < 4; ++r) x[r] += (h * ATAB[st][3]) * kv[r]; }
          }
          uint2 pk; pk.x = pack2bf(x[0], x[1]); pk.y = pack2bf(x[2], x[3]);
          *(uint2*)&sh.Pib[(16*ct + lc)*PP + 16*sr + 4*lg] = pk;
        }
        // ---- x-side: kx = MFMA(-K, (Cx - y), APdX) + Bu ----
        if (isx) {
          s16x8 bgX = load_fragT<HYP>(sh.GTb, PK, 64, 0);
          f32x4 kx = MFT<HYP>(am, bgX, APdX);               // A@xi + K(y-Cx)
          {
            f32x4 bu1 = *(const f32x4*)&sh.BUB[t & 1][rowbase];
            if (st == 0) {
              kx += bu1;
            } else {
              const float cp = CTAB[st-1];
              if (cp != 0.f) {
                f32x4 bu2 = *(const f32x4*)&sh.BUB[(t + 1) & 1][rowbase];
                kx += (1.f - cp) * bu1 + cp * bu2;
              } else {
                kx += bu1;
              }
            }
          }
          f32x4 xiv;
          if (st == 0) {
            f32x4 k0 = *(const f32x4*)&sh.KXL[0][rowbase];
            f32x4 k2 = *(const f32x4*)&sh.KXL[2][rowbase];
            f32x4 k3 = *(const f32x4*)&sh.KXL[3][rowbase];
            f32x4 k4 = *(const f32x4*)&sh.KXL[4][rowbase];
            XRv += h * (BW0*k0 + BW2*k2 + BW3*k3 + BW4*k4 + BW5*kx);
            if (lc == 0) *(f32x4*)&out[(size_t)t*64 + rowbase] = XRv;
            xiv = XRv;
          } else {
            if (lc == 0) *(f32x4*)&sh.KXL[st-1][rowbase] = kx;
            xiv = XRv + (h * ATAB[st][st-1]) * kx;
            if (st >= 2 && ATAB[st][0] != 0.f) xiv += (h * ATAB[st][0]) * (*(const f32x4*)&sh.KXL[0][rowbase]);
            if (st >= 3 && ATAB[st][1] != 0.f) xiv += (h * ATAB[st][1]) * (*(const f32x4*)&sh.KXL[1][rowbase]);
            if (st >= 4 && ATAB[st][2] != 0.f) xiv += (h * ATAB[st][2]) * (*(const f32x4*)&sh.KXL[2][rowbase]);
            if (st >= 5 && ATAB[st][3] != 0.f) xiv += (h * ATAB[st][3]) * (*(const f32x4*)&sh.KXL[3][rowbase]);
          }
          if (lc == 0) {
            uint2 pk; pk.x = pack2bf(xiv[0], xiv[1]); pk.y = pack2bf(xiv[2], xiv[3]);
            *(uint2*)&sh.Pib[64*PP + rowbase] = pk;
          }
        }
      } else {
        #pragma unroll
        for (int c2 = 0; c2 < 2; ++c2) {
          const int ct = 2*ch + c2;
          uint2 pk; pk.x = pack2bf(Pfr[c2][0], Pfr[c2][1]); pk.y = pack2bf(Pfr[c2][2], Pfr[c2][3]);
          *(uint2*)&sh.Pib[(16*ct + lc)*PP + 16*sr + 4*lg] = pk;
        }
      }
      __syncthreads();
      // ================= PHASE B =================
      {
        s16x8 aPi0 = load_fragT<HYP>(sh.Pib, PP, 16*sr, 0);
        s16x8 aPi1 = load_fragT<HYP>(sh.Pib, PP, 16*sr, 32);
        #pragma unroll
        for (int c2 = 0; c2 < 2; ++c2) {
          const int ct = 2*ch + c2;
          s16x8 bP0 = load_fragT<HYP>(sh.Pib, PP, 16*ct, 0);
          s16x8 bP1 = load_fragT<HYP>(sh.Pib, PP, 16*ct, 32);
          f32x4 acc = MFT<HYP>(aA[0], bP0, z4);
          acc = MFT<HYP>(aA[1], bP1, acc);
          acc = MFT<HYP>(aPi0, bA[c2][0], acc);
          AP[c2] = MFT<HYP>(aPi1, bA[c2][1], acc);
        }
        f32x4 aK = MFT<HYP>(aRC[1], aPi1, MFT<HYP>(aRC[0], aPi0, z4));   // = -K strip
        uint2 pkk; pkk.x = pack2bf(aK[0], aK[1]); pkk.y = pack2bf(aK[2], aK[3]);
        *(uint2*)&sh.KKb[(16*sr + lc)*PK + 16*ch + 4*lg] = pkk;
        f32x4 aG = MFT<HYP>(aC[1], aPi1, MFT<HYP>(aC[0], aPi0, z4));
        uint2 pkg; pkg.x = pack2bf(aG[0], aG[1]); pkg.y = pack2bf(aG[2], aG[3]);
        *(uint2*)&sh.GTb[(16*sr + lc)*PK + 16*ch + 4*lg] = pkg;
      }
      if (isx || isg) {
        s16x8 px0 = load_fragT<HYP>(sh.Pib, PP, 64, 0);
        s16x8 px1 = load_fragT<HYP>(sh.Pib, PP, 64, 32);
        if (isx) {
          APdX = MFT<HYP>(aA[1], px1, MFT<HYP>(aA[0], px0, z4));
        }
        if (isg) {
          f32x4 gx = MFT<HYP>(aC[1], px1, MFT<HYP>(aC[0], px0, z4));
          const float c = CTAB[st];
          f32x4 v;
          #pragma unroll
          for (int r = 0; r < 4; ++r) {
            float yc = (1.f - c) * y1v[r] + c * y2v[r];
            v[r] = gx[r] - yc;            // (Cx - y): sign pairs with -K
          }
          uint2 pk;
          if (lc == 0) { pk.x = pack2bf(v[0], v[1]); pk.y = pack2bf(v[2], v[3]); }
          else         { pk.x = 0u; pk.y = 0u; }
          *(uint2*)&sh.GTb[(64 + lc)*PK + 16*ch + 4*lg] = pk;
        }
      }
      if (st == 0 && tid < 64) {
        const f32x4* bf4 = (const f32x4*)&sh.Bf[tid*16];
        const f32x4* up4 = (const f32x4*)(us + (size_t)(t + 1)*NI);
        float bu = 0.f;
        #pragma unroll
        for (int m4 = 0; m4 < 4; ++m4) {
          f32x4 b = bf4[m4], u = up4[m4];
          bu += b.x*u.x + b.y*u.y + b.z*u.z + b.w*u.w;
        }
        sh.BUB[(t + 1) & 1][tid] = bu;
      }
      __syncthreads();
    } // stages
    if (isg) {
      y1v = y2v;
      if (t + 2 < TN) y2v = *(const f32x4*)&ys[(size_t)(t + 2)*NO + 16*ch + 4*lg];
    }
  } // t

  // tail: slope k5 of last step + final x combine
  if (isx) {
    s16x8 am  = load_fragT<HYP>(sh.KKb, PK, 16*sr, 0);
    s16x8 bgX = load_fragT<HYP>(sh.GTb, PK, 64, 0);
    f32x4 kx = MFT<HYP>(am, bgX, APdX);
    kx += *(const f32x4*)&sh.BUB[(TN - 1) & 1][rowbase];
    f32x4 k0 = *(const f32x4*)&sh.KXL[0][rowbase];
    f32x4 k2 = *(const f32x4*)&sh.KXL[2][rowbase];
    f32x4 k3 = *(const f32x4*)&sh.KXL[3][rowbase];
    f32x4 k4 = *(const f32x4*)&sh.KXL[4][rowbase];
    XRv += h * (BW0*k0 + BW2*k2 + BW3*k3 + BW4*k4 + BW5*kx);
    if (lc == 0) *(f32x4*)&out[(size_t)(TN - 1)*64 + rowbase] = XRv;
  }
}

__global__ __launch_bounds__(512, 1)
void kf_mfma14(const float* __restrict__ ts, const float* __restrict__ ys,
               const float* __restrict__ us, const float* __restrict__ Ag,
               const float* __restrict__ Bg, const float* __restrict__ Cg,
               const float* __restrict__ x0g, const float* __restrict__ P0g,
               const float* __restrict__ Qg, const float* __restrict__ Rg,
               float* __restrict__ out)
{
  extern __shared__ char dsm[];
  ShB& sh = *(ShB*)dsm;
  float* KPL = (float*)(dsm + SH_BASE);
  float* GJ  = KPL;
  const int tid = (int)threadIdx.x;
  const int wv = tid >> 6;
  const int lc = tid & 15, lg = (tid & 63) >> 4;

  for (int idx = tid; idx < 64*64; idx += 512) sh.Ab[(idx>>6)*PP + (idx&63)] = f2bf(Ag[idx]);
  for (int idx = tid; idx < 32*64; idx += 512) sh.Cb[(idx>>6)*PP + (idx&63)] = f2bf(Cg[idx]);
  for (int idx = tid; idx < 64*16; idx += 512) sh.Bf[idx] = Bg[idx];
  for (int idx = tid; idx < 32*64; idx += 512) {
    int r = idx >> 6, c = idx & 63;
    GJ[idx] = (c < 32) ? Rg[r*32 + c] : ((c - 32) == r ? 1.f : 0.f);
  }
  __syncthreads();
  for (int k2 = 0; k2 < 32; ++k2) {
    if (tid < 32) sh.FAC[tid] = GJ[tid*64 + k2];
    __syncthreads();
    const float pinv = 1.f / sh.FAC[k2];
    float oldv[4], vk[4];
    #pragma unroll
    for (int s = 0; s < 4; ++s) {
      int idx = tid + s*512;
      oldv[s] = GJ[idx];
      vk[s]   = GJ[k2*64 + (idx & 63)];
    }
    __syncthreads();
    #pragma unroll
    for (int s = 0; s < 4; ++s) {
      int idx = tid + s*512, i = idx >> 6;
      GJ[idx] = (i == k2) ? (oldv[s] * pinv) : (oldv[s] - sh.FAC[i] * (vk[s] * pinv));
    }
    __syncthreads();
  }
  for (int idx = tid; idx < 32*64; idx += 512) {   // RCb = -(Rinv @ C)
    int q = idx >> 6, k = idx & 63;
    float a = 0.f;
    for (int p = 0; p < 32; ++p) a += GJ[q*64 + 32 + p] * Cg[p*64 + k];
    sh.RCb[q*PP + k] = f2bf(-a);
  }
  __syncthreads();
  __shared__ float Xref[256];
  if (tid < 256) {
    int r = tid >> 4, c = tid & 15;
    float a = 0.f;
    for (int k = 0; k < 32; ++k) a += bf2f(sh.Ab[r*PP + k]) * bf2f(sh.Ab[(16 + c)*PP + k]);
    Xref[tid] = a;
  }
  if (tid == 0) sh.HYP = -1;
  __syncthreads();
  for (int hh = 0; hh < 4; ++hh) {
    if (wv == 0) {
      s16x8 af = load_frag(sh.Ab, PP, 0, 0, hh);
      s16x8 bf = load_frag(sh.Ab, PP, 16, 0, hh);
      f32x4 z = {0.f,0.f,0.f,0.f};
      f32x4 d = MF(af, bf, z, hh);
      int ok = 1;
      #pragma unroll
      for (int r = 0; r < 4; ++r) {
        float rf = Xref[(lg*4 + r)*16 + lc];
        ok &= (fabsf(d[r] - rf) <= 1e-3f + 1e-2f * fabsf(rf)) ? 1 : 0;
      }
      if (__all(ok) && tid == 0) { if (sh.HYP < 0) sh.HYP = hh; }
    }
    __syncthreads();
  }
  const int sHyp = (sh.HYP < 0) ? 0 : sh.HYP;

  switch (sHyp) {
    case 0: scan_body<0>(sh, KPL, ts, ys, us, x0g, P0g, Qg, out); break;
    case 1: scan_body<1>(sh, KPL, ts, ys, us, x0g, P0g, Qg, out); break;
    case 2: scan_body<2>(sh, KPL, ts, ys, us, x0g, P0g, Qg, out); break;
    default: scan_body<3>(sh, KPL, ts, ys, us, x0g, P0g, Qg, out); break;
  }
}

extern "C" void kernel_launch(void* const* d_in, const int* in_sizes, int n_in,
                              void* d_out, int out_size, void* d_ws, size_t ws_size,
                              hipStream_t stream) {
  (void)in_sizes; (void)n_in; (void)out_size; (void)d_ws; (void)ws_size;
  const float* ts  = (const float*)d_in[0];
  const float* ys  = (const float*)d_in[1];
  const float* us  = (const float*)d_in[2];
  const float* A   = (const float*)d_in[3];
  const float* B   = (const float*)d_in[4];
  const float* C   = (const float*)d_in[5];
  const float* x0  = (const float*)d_in[6];
  const float* P0  = (const float*)d_in[7];
  const float* Q   = (const float*)d_in[8];
  const float* R   = (const float*)d_in[9];
  (void)hipFuncSetAttribute(reinterpret_cast<const void*>(kf_mfma14),
                            hipFuncAttributeMaxDynamicSharedMemorySize, (int)SH_TOTAL);
  hipLaunchKernelGGL(kf_mfma14, dim3(1), dim3(512), SH_TOTAL, stream,
                     ts, ys, us, A, B, C, x0, P0, Q, R, (float*)d_out);
}